// Round 2
// 1112.001 us; speedup vs baseline: 1.0491x; 1.0491x over previous
//
#include <hip/hip_runtime.h>
#include <hip/hip_bf16.h>
#include <cstdint>

// Problem constants
#define BB 4096
#define FF 2048
#define HD 2048           // H*D = 16*128
#define PROJ_N 2730
#define UPN 5460          // 2*PROJ
#define UPN_PAD 5504      // 43*128
#define DK_PAD 2752       // 86*32 (down K padded)

typedef __attribute__((ext_vector_type(8))) short bf16x8;
typedef __attribute__((ext_vector_type(4))) float f32x4;

__device__ __forceinline__ unsigned short f2bf(float f) {
  union { float f; unsigned int u; } x; x.f = f;
  unsigned int r = x.u + 0x7fffu + ((x.u >> 16) & 1u);
  return (unsigned short)(r >> 16);
}

// ---------------------------------------------------------------------------
// Kernel 1: LayerNorm + x_prev shift + n-all-zero flag
// ---------------------------------------------------------------------------
__global__ __launch_bounds__(256) void ln_prep(
    const float* __restrict__ inputs, const float* __restrict__ x_prev,
    const float* __restrict__ n_state,
    const float* __restrict__ ln_scale, const float* __restrict__ ln_bias,
    unsigned short* __restrict__ x_t_bf, float* __restrict__ xprev_out,
    int* __restrict__ flags)
{
  int b = blockIdx.x, t = threadIdx.x;
  const float* row = inputs + ((long)b << 11);
  float x[8];
  {
    float4 a = *(const float4*)(row + t * 8);
    float4 c = *(const float4*)(row + t * 8 + 4);
    x[0]=a.x; x[1]=a.y; x[2]=a.z; x[3]=a.w; x[4]=c.x; x[5]=c.y; x[6]=c.z; x[7]=c.w;
  }
  float s = 0.f, sq = 0.f;
#pragma unroll
  for (int k = 0; k < 8; ++k) { s += x[k]; sq += x[k] * x[k]; }

  const float* nrow = n_state + ((long)b << 11);
  int nz;
  {
    float4 a = *(const float4*)(nrow + t * 8);
    float4 c = *(const float4*)(nrow + t * 8 + 4);
    nz = (a.x != 0.f) | (a.y != 0.f) | (a.z != 0.f) | (a.w != 0.f) |
         (c.x != 0.f) | (c.y != 0.f) | (c.z != 0.f) | (c.w != 0.f);
  }

#pragma unroll
  for (int off = 32; off >= 1; off >>= 1) {
    s  += __shfl_xor(s, off);
    sq += __shfl_xor(sq, off);
  }
  __shared__ float ws_s[4], ws_q[4];
  __shared__ int s_nz;
  if (t == 0) s_nz = 0;
  __syncthreads();
  if (nz) s_nz = 1;                       // benign race, same value
  int wave = t >> 6;
  if ((t & 63) == 0) { ws_s[wave] = s; ws_q[wave] = sq; }
  __syncthreads();
  float ts = ws_s[0] + ws_s[1] + ws_s[2] + ws_s[3];
  float tq = ws_q[0] + ws_q[1] + ws_q[2] + ws_q[3];
  float mu  = ts * (1.f / 2048.f);
  float var = tq * (1.f / 2048.f) - mu * mu;
  float rs  = rsqrtf(var + 2048.0f);      // LN_EPS = float(F) = 2048

  unsigned short outb[8];
  float y[8];
#pragma unroll
  for (int k = 0; k < 8; ++k) {
    int c = t * 8 + k;
    float v = (x[k] - mu) * rs * ln_scale[c] + ln_bias[c];
    y[k] = v;
    outb[k] = f2bf(v);
  }
  *(uint4*)&x_t_bf[((long)b << 11) + t * 8] = *(uint4*)outb;
  float* xo = xprev_out + (long)b * 6144 + 4096 + t * 8;
  *(float4*)(xo)     = make_float4(y[0], y[1], y[2], y[3]);
  *(float4*)(xo + 4) = make_float4(y[4], y[5], y[6], y[7]);
  const float* src = x_prev + (long)b * 6144 + 2048;
  float* dst = xprev_out + (long)b * 6144;
  for (int i = t; i < 1024; i += 256)
    *(float4*)(dst + i * 4) = *(const float4*)(src + i * 4);
  if (t == 0) flags[b] = (s_nz == 0) ? 1 : 0;
}

// ---------------------------------------------------------------------------
// Kernel 2: transpose + cast fp32 (R x C) -> bf16 (OC x OK), zero padded.
// ---------------------------------------------------------------------------
__global__ __launch_bounds__(256) void transpose_cast(
    const float* __restrict__ in, unsigned short* __restrict__ out,
    int R, int C, int OC, int OK)
{
  __shared__ float tile[32][33];
  int ro0 = blockIdx.x * 32;
  int co0 = blockIdx.y * 32;
  int tx = threadIdx.x & 31, ty = threadIdx.x >> 5;
#pragma unroll
  for (int i = 0; i < 4; ++i) {
    int r = ro0 + ty + i * 8, cc = co0 + tx;
    float v = (r < R && cc < C) ? in[(long)r * C + cc] : 0.f;
    tile[ty + i * 8][tx] = v;
  }
  __syncthreads();
#pragma unroll
  for (int i = 0; i < 4; ++i) {
    int oc = co0 + ty + i * 8, ok = ro0 + tx;
    if (oc < OC && ok < OK)
      out[(long)oc * OK + ok] = f2bf(tile[tx][ty + i * 8]);
  }
}

// ---------------------------------------------------------------------------
// Kernel 3: 256x256 8-phase NT bf16 MFMA GEMM (m201-class schedule).
//   C[m][n] = sum_k A[m][k] * Bt[n][k]  (+bias +resid)
//   BK=64, 512 threads = 8 waves (2M x 4N), per-wave output 128x64.
//   LDS 128 KiB STATIC: 2 bufs x [A 256x64 | B 256x64] bf16.
//
//   Swizzle (T2): within each 128B LDS row, colbyte ^= (row&7)<<4.
//     Staging keeps LDS dest LINEAR (global_load_lds rule) and pre-swizzles
//     the per-lane GLOBAL source column: per-issue row = lane>>3,
//     slot = lane&7 -> src col = ((l7^l8)<<3) elems.  Since row&7 == lane>>3
//     for every staged region, LDS[row][slot s] = global[row][s ^ (row&7)].
//     Fragment ds_read_b128 at slot (q ^ (row&7)) then recovers logical
//     slot q; 64 lanes spread across all 8 16B-slots -> ~2-way (free).
//   B rows are LDS-permuted: rho = cb*128 + wn-chunk layout so each staged
//     chunk (rows consumed together by wave wn) is LDS-contiguous.
//
//   Schedule per K-tile t (c = buf t&1, o = other; 4 phases):
//     p1: ds A(rb0)+B(cb0) | issue t+1 B0..B3 -> buf o | MFMA rb0 x cb0
//     p2: ds B(cb1)        | issue t+2 A0     -> buf c | MFMA rb0 x cb1
//     p3: ds A(rb1)        |                           | MFMA rb1 x cb1
//     p4:                  | issue t+2 A1 -> buf c | vmcnt(4) | MFMA rb1 x cb0
//   Every DMA issue lands in a region whose last ds_read was >=1 barrier
//   earlier (all waves drained via their own lgkmcnt(0) before that barrier).
//   vmcnt(4) at p4 drains all of tile t+1 while keeping t+2's A (4 loads) in
//   flight -> never drains to 0 in the main loop (T3/T4).  Tail: t1/t2 clamp
//   to NT-1 (duplicate loads into already-consumed regions: harmless).
//   vmcnt(0) before epilogue so no LDS-DMA is outstanding at s_endpgm.
// ---------------------------------------------------------------------------
#define P_PRE()  do { __builtin_amdgcn_s_barrier(); \
                      asm volatile("s_waitcnt lgkmcnt(0)" ::: "memory"); \
                      __builtin_amdgcn_sched_barrier(0); \
                      __builtin_amdgcn_s_setprio(1); } while (0)
#define P_POST() do { __builtin_amdgcn_s_setprio(0); \
                      __builtin_amdgcn_sched_barrier(0); \
                      __builtin_amdgcn_s_barrier(); \
                      __builtin_amdgcn_sched_barrier(0); } while (0)

#define STAGE_A(h, k2, bo, kt)                                               \
  __builtin_amdgcn_global_load_lds(                                          \
      (const __attribute__((address_space(1))) void*)(pA[h][k2] + (long)(kt)*64), \
      (__attribute__((address_space(3))) void*)(ldsA + (bo) + ((k2)*16384 + (h)*8192) + wvu*1024), \
      16, 0, 0)
#define STAGE_B(cb, i, bo, kt)                                               \
  __builtin_amdgcn_global_load_lds(                                          \
      (const __attribute__((address_space(1))) void*)(pB[cb][i] + (long)(kt)*64), \
      (__attribute__((address_space(3))) void*)(ldsB + (bo) + ((cb)*16384 + (i)*8192) + wvu*1024), \
      16, 0, 0)

#define LOAD_A(rb, bo)                                                       \
  { _Pragma("unroll")                                                        \
    for (int f = 0; f < 4; ++f) {                                            \
      const char* p_ = ldsA + (bo) + (unsigned)((wm*128 + (rb)*64 + f*16 + m16) << 7); \
      aF[f][0] = *(const bf16x8*)(p_ + s0);                                  \
      aF[f][1] = *(const bf16x8*)(p_ + s1);                                  \
    } }
#define LOAD_B(cb, BV, bo)                                                   \
  { _Pragma("unroll")                                                        \
    for (int f = 0; f < 2; ++f) {                                            \
      const char* p_ = ldsB + (bo) + (unsigned)(((cb)*128 + wn*32 + f*16 + m16) << 7); \
      BV[f][0] = *(const bf16x8*)(p_ + s0);                                  \
      BV[f][1] = *(const bf16x8*)(p_ + s1);                                  \
    } }
#define MFMA_PH(rb, cb, BV)                                                  \
  { _Pragma("unroll")                                                        \
    for (int f = 0; f < 4; ++f) {                                            \
      acc[(rb)*4+f][(cb)*2+0] = __builtin_amdgcn_mfma_f32_16x16x32_bf16(     \
          aF[f][0], BV[0][0], acc[(rb)*4+f][(cb)*2+0], 0, 0, 0);             \
      acc[(rb)*4+f][(cb)*2+1] = __builtin_amdgcn_mfma_f32_16x16x32_bf16(     \
          aF[f][0], BV[1][0], acc[(rb)*4+f][(cb)*2+1], 0, 0, 0);             \
      acc[(rb)*4+f][(cb)*2+0] = __builtin_amdgcn_mfma_f32_16x16x32_bf16(     \
          aF[f][1], BV[0][1], acc[(rb)*4+f][(cb)*2+0], 0, 0, 0);             \
      acc[(rb)*4+f][(cb)*2+1] = __builtin_amdgcn_mfma_f32_16x16x32_bf16(     \
          aF[f][1], BV[1][1], acc[(rb)*4+f][(cb)*2+1], 0, 0, 0);             \
    } }

__global__ __launch_bounds__(512) void gemm8(
    const unsigned short* __restrict__ A, const unsigned short* __restrict__ Bt,
    float* __restrict__ C, int K, int lda, int ldb, int ldc,
    int Nreal, int NBmax,
    const float* __restrict__ bias, const float* __restrict__ resid,
    long strideB, long strideC)
{
  // 128 KiB static LDS (gfx950 workgroup limit is 160 KiB)
  __shared__ __attribute__((aligned(1024))) char smem[131072];
  char* ldsA = smem;            // 2 x 32768 B
  char* ldsB = smem + 65536;    // 2 x 32768 B

  Bt += (long)blockIdx.z * strideB;
  C  += (long)blockIdx.z * strideC;

  const int tid  = threadIdx.x;
  const int lane = tid & 63, wvu = tid >> 6;
  const int wm = wvu >> 2, wn = wvu & 3;        // 2M x 4N waves
  const int m16 = lane & 15, qd = lane >> 4;

  // T1: bijective XCD swizzle on the 2D grid (z untouched)
  int nwg = gridDim.x * gridDim.y;
  int lin = blockIdx.y * gridDim.x + blockIdx.x;
  int qq_ = nwg >> 3, rr_ = nwg & 7, xcd = lin & 7, idx8 = lin >> 3;
  int swz = (xcd < rr_ ? xcd * (qq_ + 1) : rr_ * (qq_ + 1) + (xcd - rr_) * qq_) + idx8;
  int bx = swz % gridDim.x, by = swz / gridDim.x;
  const int n0 = bx * 256, m0 = by * 256;

  // ---- staging source pointers (per lane, pre-swizzled global column) ----
  const int l8 = lane >> 3, l7 = lane & 7;
  const int scol = ((l7 ^ l8) << 3);            // inverse-swizzled col (elems)
  const unsigned short *pA[2][2], *pB[2][2];
#pragma unroll
  for (int h = 0; h < 2; ++h)
#pragma unroll
    for (int k2 = 0; k2 < 2; ++k2) {
      int row = m0 + k2 * 128 + h * 64 + wvu * 8 + l8;
      pA[h][k2] = A + (long)row * lda + scol;
    }
#pragma unroll
  for (int cb = 0; cb < 2; ++cb)
#pragma unroll
    for (int i = 0; i < 2; ++i) {
      int qq = i * 64 + wvu * 8 + l8;                 // rho within chunk pair
      int n  = ((qq >> 5) << 6) + cb * 32 + (qq & 31);
      int gr = n0 + n; if (gr > NBmax - 1) gr = NBmax - 1;   // clamp (up GEMM)
      pB[cb][i] = Bt + (long)gr * ldb + scol;
    }

  // swizzled ds_read slot offsets (bytes within a 128B LDS row)
  const int s0 = ((qd ^ (m16 & 7)) << 4);
  const int s1 = s0 ^ 64;                       // logical slot qd+4, swizzled

  f32x4 acc[8][4] = {};
  bf16x8 aF[4][2], b0v[2][2], b1v[2][2];

  const int NT  = K >> 6;
  const int t1p = (NT > 1) ? 1 : 0;

  // ---- prologue: T0 {A,B}, T1 {A}; keep T1's 4 loads in flight
  STAGE_A(0,0,0,0); STAGE_A(0,1,0,0);
  STAGE_B(0,0,0,0); STAGE_B(0,1,0,0);
  STAGE_B(1,0,0,0); STAGE_B(1,1,0,0);
  STAGE_A(1,0,0,0); STAGE_A(1,1,0,0);
  STAGE_A(0,0,32768,t1p); STAGE_A(0,1,32768,t1p);
  STAGE_A(1,0,32768,t1p); STAGE_A(1,1,32768,t1p);
  asm volatile("s_waitcnt vmcnt(4)" ::: "memory");
  __builtin_amdgcn_s_barrier();
  __builtin_amdgcn_sched_barrier(0);

  for (int t = 0; t < NT; ++t) {
    const int co = (t & 1) << 15;
    const int oo = co ^ 32768;
    const int t1 = (t + 1 < NT) ? t + 1 : NT - 1;
    const int t2 = (t + 2 < NT) ? t + 2 : NT - 1;
    // ---- phase 1: quadrant rb0 x cb0
    LOAD_A(0, co);
    LOAD_B(0, b0v, co);
    STAGE_B(0,0,oo,t1); STAGE_B(0,1,oo,t1);
    STAGE_B(1,0,oo,t1); STAGE_B(1,1,oo,t1);
    P_PRE(); MFMA_PH(0,0,b0v); P_POST();
    // ---- phase 2: quadrant rb0 x cb1
    LOAD_B(1, b1v, co);
    STAGE_A(0,0,co,t2); STAGE_A(0,1,co,t2);
    P_PRE(); MFMA_PH(0,1,b1v); P_POST();
    // ---- phase 3: quadrant rb1 x cb1
    LOAD_A(1, co);
    P_PRE(); MFMA_PH(1,1,b1v); P_POST();
    // ---- phase 4: quadrant rb1 x cb0 (b0v kept since p1)
    STAGE_A(1,0,co,t2); STAGE_A(1,1,co,t2);
    asm volatile("s_waitcnt vmcnt(4)" ::: "memory");
    P_PRE(); MFMA_PH(1,0,b0v); P_POST();
  }
  // drain outstanding LDS-DMA before epilogue / endpgm
  asm volatile("s_waitcnt vmcnt(0)" ::: "memory");

  // ---- epilogue ----
#pragma unroll
  for (int mf = 0; mf < 8; ++mf) {
    int gm = m0 + wm * 128 + mf * 16 + qd * 4;
#pragma unroll
    for (int nf = 0; nf < 4; ++nf) {
      int gn = n0 + wn * 64 + nf * 16 + m16;
      if (gn < Nreal) {
        float badd = bias ? bias[gn] : 0.f;
#pragma unroll
        for (int r = 0; r < 4; ++r) {
          float v = acc[mf][nf][r] + badd;
          if (resid) v += resid[(long)(gm + r) * ldc + gn];
          C[(long)(gm + r) * ldc + gn] = v;
        }
      }
    }
  }
}

// ---------------------------------------------------------------------------
// Kernel 4: pointwise sLSTM
// ---------------------------------------------------------------------------
__global__ __launch_bounds__(256) void slstm_pointwise(
    const float* __restrict__ g_i, const float* __restrict__ g_f,
    const float* __restrict__ g_z, const float* __restrict__ g_o,
    const float* __restrict__ Wib, const float* __restrict__ Wfb,
    const float* __restrict__ Wzb, const float* __restrict__ Wob,
    const float* __restrict__ Ri, const float* __restrict__ Rf,
    const float* __restrict__ Rz, const float* __restrict__ Ro,
    const float* __restrict__ Rib, const float* __restrict__ Rfb,
    const float* __restrict__ Rzb, const float* __restrict__ Rob,
    const float* __restrict__ c_in, const float* __restrict__ n_in,
    const float* __restrict__ h_in, const float* __restrict__ m_in,
    const int* __restrict__ flags,
    float* __restrict__ c_out, float* __restrict__ n_out,
    float* __restrict__ h_out, float* __restrict__ m_out)
{
  int idx = blockIdx.x * 256 + threadIdx.x;
  int b = idx >> 11, j = idx & 2047;
  int hh = j >> 7, nb = (j >> 3) & 15, e = j & 7;
  const float* hp = h_in + ((long)b << 11) + hh * 128 + nb * 8;
  float hv[8];
#pragma unroll
  for (int d = 0; d < 8; ++d) hv[d] = hp[d];
  int rb = nb * 64 + e;
  float reci = Rib[nb * 8 + e], recf = Rfb[nb * 8 + e];
  float recz = Rzb[nb * 8 + e], reco = Rob[nb * 8 + e];
#pragma unroll
  for (int d = 0; d < 8; ++d) {
    reci += hv[d] * Ri[rb + d * 8];
    recf += hv[d] * Rf[rb + d * 8];
    recz += hv[d] * Rz[rb + d * 8];
    reco += hv[d] * Ro[rb + d * 8];
  }
  float iraw = g_i[idx] + Wib[j] + reci;
  float fraw = g_f[idx] + Wfb[j] + recf;
  float zraw = g_z[idx] + Wzb[j] + recz;
  float oraw = g_o[idx] + Wob[j] + reco;
  float mo = m_in[idx];
  float ls = fminf(fraw, 0.f) - log1pf(expf(-fabsf(fraw)));
  float lfpm = mo + ls;
  float mt = flags[b] ? iraw : fmaxf(iraw, lfpm);
  float ot = 1.f / (1.f + expf(-oraw));
  float it = expf(iraw - mt);
  float ft = expf(lfpm - mt);
  float zt = tanhf(zraw);
  float ct = ft * c_in[idx] + it * zt;
  float nt = ft * n_in[idx] + it;
  float ht = ot * ct / (nt + 1e-8f);
  c_out[idx] = ct; n_out[idx] = nt; h_out[idx] = ht; m_out[idx] = mt;
}

// ---------------------------------------------------------------------------
// Kernel 5: GroupNorm -> bf16
// ---------------------------------------------------------------------------
__global__ __launch_bounds__(256) void groupnorm(
    const float* __restrict__ h_t, const float* __restrict__ gn_scale,
    const float* __restrict__ gn_bias, unsigned short* __restrict__ outn)
{
  int b = blockIdx.x, t = threadIdx.x;
  const float* row = h_t + ((long)b << 11);
  float x[8];
  {
    float4 a = *(const float4*)(row + t * 8);
    float4 c = *(const float4*)(row + t * 8 + 4);
    x[0]=a.x; x[1]=a.y; x[2]=a.z; x[3]=a.w; x[4]=c.x; x[5]=c.y; x[6]=c.z; x[7]=c.w;
  }
  float s = 0.f, sq = 0.f;
#pragma unroll
  for (int k = 0; k < 8; ++k) { s += x[k]; sq += x[k] * x[k]; }
  __shared__ float s1[256], s2[256];
  s1[t] = s; s2[t] = sq;
  __syncthreads();
  for (int st = 128; st >= 16; st >>= 1) {
    if (t < st) { s1[t] += s1[t + st]; s2[t] += s2[t + st]; }
    __syncthreads();
  }
  int g = t & 15;
  float mu  = s1[g] * (1.f / 128.f);
  float var = s2[g] * (1.f / 128.f) - mu * mu;
  float rs  = rsqrtf(var + 1e-6f);
  unsigned short ob[8];
#pragma unroll
  for (int k = 0; k < 8; ++k) {
    int j = t * 8 + k;
    int dd = j & 127;
    ob[k] = f2bf((x[k] - mu) * rs * gn_scale[dd] + gn_bias[dd]);
  }
  *(uint4*)&outn[((long)b << 11) + t * 8] = *(uint4*)ob;
}

// ---------------------------------------------------------------------------
// Kernel 6: o1 * gelu(o2) with bias, write bf16 K-padded
// ---------------------------------------------------------------------------
__global__ __launch_bounds__(256) void gelu_mult(
    const float* __restrict__ u, const float* __restrict__ up_b,
    unsigned short* __restrict__ Hg)
{
  int idx = blockIdx.x * 256 + threadIdx.x;
  if (idx >= BB * DK_PAD) return;
  int b = idx / DK_PAD, p = idx - b * DK_PAD;
  unsigned short r = 0;
  if (p < PROJ_N) {
    const float* ur = u + (long)b * UPN_PAD;
    float o1 = ur[p] + up_b[p];
    float o2 = ur[PROJ_N + p] + up_b[PROJ_N + p];
    float tt = o2 + 0.044715f * o2 * o2 * o2;
    float g = 0.5f * o2 * (1.f + tanhf(0.7978845608028654f * tt));
    r = f2bf(o1 * g);
  }
  Hg[idx] = r;
}

// ---------------------------------------------------------------------------
extern "C" void kernel_launch(void* const* d_in, const int* in_sizes, int n_in,
                              void* d_out, int out_size, void* d_ws, size_t ws_size,
                              hipStream_t stream)
{
  const float* inputs  = (const float*)d_in[0];
  const float* c_in    = (const float*)d_in[1];
  const float* n_st    = (const float*)d_in[2];
  const float* h_in    = (const float*)d_in[3];
  const float* m_in    = (const float*)d_in[4];
  const float* x_prev  = (const float*)d_in[5];
  const float* ln_s    = (const float*)d_in[6];
  const float* ln_b    = (const float*)d_in[7];
  const float* Wz = (const float*)d_in[8];  const float* Wzb = (const float*)d_in[9];
  const float* Rz = (const float*)d_in[10]; const float* Rzb = (const float*)d_in[11];
  const float* Wi = (const float*)d_in[12]; const float* Wib = (const float*)d_in[13];
  const float* Ri = (const float*)d_in[14]; const float* Rib = (const float*)d_in[15];
  const float* Wf = (const float*)d_in[16]; const float* Wfb = (const float*)d_in[17];
  const float* Rf = (const float*)d_in[18]; const float* Rfb = (const float*)d_in[19];
  const float* Wo = (const float*)d_in[20]; const float* Wob = (const float*)d_in[21];
  const float* Ro = (const float*)d_in[22]; const float* Rob = (const float*)d_in[23];
  const float* gn_s = (const float*)d_in[24]; const float* gn_b = (const float*)d_in[25];
  const float* up_k = (const float*)d_in[26]; const float* up_b = (const float*)d_in[27];
  const float* dn_k = (const float*)d_in[28]; const float* dn_b = (const float*)d_in[29];

  // Workspace layout (lifetime-aliased):
  char* ws = (char*)d_ws;
  float* g_raw = (float*)ws;                                     // 4 x 33.55MB
  float* u_buf = (float*)ws;                                     // alias (after pointwise)
  unsigned short* x_t_bf = (unsigned short*)(ws + 134217728);    // 16.78MB
  unsigned short* outn_bf = x_t_bf;                              // alias (after gates)
  unsigned short* Wt  = (unsigned short*)(ws + 150994944);       // 4 x 8.39MB
  unsigned short* upT = (unsigned short*)(ws + 184549376);       // 22.54MB
  unsigned short* Hg  = upT;                                     // alias (after up gemm)
  unsigned short* dkT = (unsigned short*)(ws + 207093760);       // 11.27MB
  int* flags = (int*)(ws + 218365952);                           // 16KB

  float* out   = (float*)d_out;
  float* out_c = out + (long)1 * 8388608;
  float* out_n = out + (long)2 * 8388608;
  float* out_h = out + (long)3 * 8388608;
  float* out_m = out + (long)4 * 8388608;
  float* out_xp = out + (long)5 * 8388608;

  // 1. LN + x_prev shift + flags
  ln_prep<<<BB, 256, 0, stream>>>(inputs, x_prev, n_st, ln_s, ln_b, x_t_bf, out_xp, flags);

  // 2. transpose-casts (gate order i,f,z,o)
  transpose_cast<<<dim3(64, 64), 256, 0, stream>>>(Wi, Wt + 0L * 4194304, 2048, 2048, 2048, 2048);
  transpose_cast<<<dim3(64, 64), 256, 0, stream>>>(Wf, Wt + 1L * 4194304, 2048, 2048, 2048, 2048);
  transpose_cast<<<dim3(64, 64), 256, 0, stream>>>(Wz, Wt + 2L * 4194304, 2048, 2048, 2048, 2048);
  transpose_cast<<<dim3(64, 64), 256, 0, stream>>>(Wo, Wt + 3L * 4194304, 2048, 2048, 2048, 2048);
  transpose_cast<<<dim3(64, 172), 256, 0, stream>>>(up_k, upT, 2048, UPN, UPN_PAD, 2048);
  transpose_cast<<<dim3(86, 64), 256, 0, stream>>>(dn_k, dkT, PROJ_N, 2048, 2048, DK_PAD);

  // 3. gate GEMMs: x_t(4096x2048) @ W^T -> g_raw[4]   (grid 8x16x4, 512thr)
  gemm8<<<dim3(8, 16, 4), 512, 0, stream>>>(x_t_bf, Wt, g_raw,
      2048, 2048, 2048, 2048, 2048, 2048, nullptr, nullptr, 4194304L, 8388608L);

  // 4. pointwise sLSTM
  slstm_pointwise<<<32768, 256, 0, stream>>>(
      g_raw, g_raw + 8388608L, g_raw + 2L * 8388608, g_raw + 3L * 8388608,
      Wib, Wfb, Wzb, Wob, Ri, Rf, Rz, Ro, Rib, Rfb, Rzb, Rob,
      c_in, n_st, h_in, m_in, flags, out_c, out_n, out_h, out_m);

  // 5. GroupNorm -> outn bf16
  groupnorm<<<BB, 256, 0, stream>>>(out_h, gn_s, gn_b, outn_bf);

  // 6. up GEMM: outn @ up_k -> u (N=5504, 22 n-blocks w/ store guard + B clamp)
  gemm8<<<dim3(22, 16, 1), 512, 0, stream>>>(outn_bf, upT, u_buf,
      2048, 2048, 2048, UPN_PAD, UPN_PAD, UPN_PAD, nullptr, nullptr, 0L, 0L);

  // 7. o1 * gelu(o2) -> Hg bf16 (K-padded)
  gelu_mult<<<(BB * DK_PAD) / 256, 256, 0, stream>>>(u_buf, up_b, Hg);

  // 8. down GEMM + bias + residual -> out (K=2752 -> NT=43)
  gemm8<<<dim3(8, 16, 1), 512, 0, stream>>>(Hg, dkT, out,
      DK_PAD, DK_PAD, DK_PAD, 2048, 2048, 2048, dn_b, inputs, 0L, 0L);
}